// Round 6
// baseline (1753.162 us; speedup 1.0000x reference)
//
#include <hip/hip_runtime.h>

// MsCorrBlock: B=8 T=8 C=256 PL=64 CR=16 H=W=56 HW=3136 NT=64 PS=7 KK=49
// Output dtype: FLOAT32 (205,520,896 B). BNI = 1/sqrt(1+1e-5).

#define MSC_BNI 0.9999950000374997f

static __device__ __forceinline__ float b2f(unsigned short h) {
  return __uint_as_float(((unsigned int)h) << 16);
}
static __device__ __forceinline__ unsigned short f2b(float f) {
  unsigned int u = __float_as_uint(f);
  u = u + 0x7FFFu + ((u >> 16) & 1u);   // round to nearest even
  return (unsigned short)(u >> 16);
}

// K1: per-channel temporal conv (K=1/3/5/7 by channel quarter), x fp32 -> A bf16.
__global__ __launch_bounds__(256) void k1_tconv(
    const float* x, unsigned short* A,
    const float* w1, const float* w3, const float* w5, const float* w7) {
  int i = blockIdx.x * 256 + threadIdx.x;       // over 8*256*3136 = 6,422,528
  if (i >= 6422528) return;
  int hw = i % 3136;
  int bc = i / 3136;
  int c = bc & 255;
  int b = bc >> 8;
  int q = c >> 6, cc = c & 63;
  float wf[7];
#pragma unroll
  for (int k = 0; k < 7; k++) wf[k] = 0.f;
  if (q == 0) { wf[3] = w1[cc]; }
  else if (q == 1) { wf[2] = w3[cc*3]; wf[3] = w3[cc*3+1]; wf[4] = w3[cc*3+2]; }
  else if (q == 2) { wf[1] = w5[cc*5]; wf[2] = w5[cc*5+1]; wf[3] = w5[cc*5+2]; wf[4] = w5[cc*5+3]; wf[5] = w5[cc*5+4]; }
  else { wf[0] = w7[cc*7]; wf[1] = w7[cc*7+1]; wf[2] = w7[cc*7+2]; wf[3] = w7[cc*7+3]; wf[4] = w7[cc*7+4]; wf[5] = w7[cc*7+5]; wf[6] = w7[cc*7+6]; }

  int base = (b * 8 * 256 + c) * 3136 + hw;     // t=0 element
  int tstr = 256 * 3136;
  float xv[8];
#pragma unroll
  for (int t = 0; t < 8; t++) xv[t] = x[base + t * tstr];
#pragma unroll
  for (int t = 0; t < 8; t++) {
    float a = 0.f;
#pragma unroll
    for (int d = -3; d <= 3; d++) {
      int ts = t + d;
      if (ts >= 0 && ts < 8) a = fmaf(wf[d + 3], xv[ts], a);
    }
    A[base + t * tstr] = f2b(a);
  }
}

// K2: 1x1 conv 256->64 + BN + ReLU.  A bf16 -> R2 fp32.  LDS 16 KB.
__global__ __launch_bounds__(256) void k2_conv1(
    const unsigned short* A, float* R2,
    const float* w, const float* g, const float* bb) {
  __shared__ float As[256][16];
  int n = blockIdx.x / 196;
  int hw0 = (blockIdx.x % 196) * 16;
  const unsigned short* Ab = A + n * 256 * 3136 + hw0;
  for (int idx = threadIdx.x; idx < 4096; idx += 256) {
    int r = idx >> 4, cl = idx & 15;
    As[r][cl] = b2f(Ab[r * 3136 + cl]);
  }
  __syncthreads();
  int o = threadIdx.x >> 2;                     // 0..63
  int j0 = (threadIdx.x & 3) * 4;
  float a0 = 0.f, a1 = 0.f, a2 = 0.f, a3 = 0.f;
  const float* wr = w + o * 256;
  for (int c = 0; c < 256; c++) {
    float wv = wr[c];
    a0 = fmaf(wv, As[c][j0 + 0], a0);
    a1 = fmaf(wv, As[c][j0 + 1], a1);
    a2 = fmaf(wv, As[c][j0 + 2], a2);
    a3 = fmaf(wv, As[c][j0 + 3], a3);
  }
  float s = g[o] * MSC_BNI, bo = bb[o];
  int off = (n * 64 + o) * 3136 + hw0 + j0;
  R2[off + 0] = fmaxf(fmaf(a0, s, bo), 0.f);
  R2[off + 1] = fmaxf(fmaf(a1, s, bo), 0.f);
  R2[off + 2] = fmaxf(fmaf(a2, s, bo), 0.f);
  R2[off + 3] = fmaxf(fmaf(a3, s, bo), 0.f);
}

// K3: 1x1 conv 64->16 + BN + ReLU.  R2 -> Y.  LDS 16 KB.
__global__ __launch_bounds__(256) void k3_conv21(
    const float* R2, float* Y,
    const float* w, const float* g, const float* bb) {
  __shared__ float As[64][64];
  int n = blockIdx.x / 49;
  int hw0 = (blockIdx.x % 49) * 64;
  const float* Rb = R2 + n * 64 * 3136 + hw0;
  for (int idx = threadIdx.x; idx < 4096; idx += 256) {
    int r = idx >> 6, cl = idx & 63;
    As[r][cl] = Rb[r * 3136 + cl];
  }
  __syncthreads();
  int o = threadIdx.x >> 4;                     // 0..15
  int j0 = (threadIdx.x & 15) * 4;
  float a0 = 0.f, a1 = 0.f, a2 = 0.f, a3 = 0.f;
  const float* wr = w + o * 64;
  for (int c = 0; c < 64; c++) {
    float wv = wr[c];
    a0 = fmaf(wv, As[c][j0 + 0], a0);
    a1 = fmaf(wv, As[c][j0 + 1], a1);
    a2 = fmaf(wv, As[c][j0 + 2], a2);
    a3 = fmaf(wv, As[c][j0 + 3], a3);
  }
  float s = g[o] * MSC_BNI, bo = bb[o];
  int off = (n * 16 + o) * 3136 + hw0 + j0;
  Y[off + 0] = fmaxf(fmaf(a0, s, bo), 0.f);
  Y[off + 1] = fmaxf(fmaf(a1, s, bo), 0.f);
  Y[off + 2] = fmaxf(fmaf(a2, s, bo), 0.f);
  Y[off + 3] = fmaxf(fmaf(a3, s, bo), 0.f);
}

// K4: 7x7-displacement correlation (vs t+1 clamped frame) /16 + BN + ReLU.
// Y (NT,16,HW) -> CO (NT,49,HW).  LDS ~38.8 KB.
__global__ __launch_bounds__(256) void k4_corr(
    const float* Y, float* CO, const float* g, const float* bb) {
  __shared__ float sb[10][16][62];              // rows h0-3..h0+6, ch, cols -3..58
  int n = blockIdx.x / 14;
  int h0 = (blockIdx.x % 14) * 4;
  int t = n & 7;
  int n2 = (t < 7) ? n + 1 : n;
  const float* Yb = Y + n2 * 16 * 3136;
  for (int idx = threadIdx.x; idx < 9920; idx += 256) {
    int r = idx / 992;
    int rem = idx - r * 992;
    int ch = rem / 62;
    int cl = rem - ch * 62;
    int gr = h0 - 3 + r, gc = cl - 3;
    float v = 0.f;
    if (gr >= 0 && gr < 56 && gc >= 0 && gc < 56)
      v = Yb[ch * 3136 + gr * 56 + gc];
    sb[r][ch][cl] = v;
  }
  __syncthreads();
  int pos = threadIdx.x;
  if (pos < 224) {
    int hl = pos / 56, wcol = pos - (pos / 56) * 56;
    float a[16];
    const float* Ya = Y + n * 16 * 3136 + (h0 + hl) * 56 + wcol;
#pragma unroll
    for (int c = 0; c < 16; c++) a[c] = Ya[c * 3136];
    float* Cp = CO + n * 49 * 3136 + (h0 + hl) * 56 + wcol;
    for (int di = 0; di < 7; di++) {
      for (int dj = 0; dj < 7; dj++) {
        float s = 0.f;
#pragma unroll
        for (int c = 0; c < 16; c++) s = fmaf(a[c], sb[hl + di][c][wcol + dj], s);
        int k = di * 7 + dj;
        float v = fmaf(s * 0.0625f, g[k] * MSC_BNI, bb[k]);
        Cp[k * 3136] = fmaxf(v, 0.f);
      }
    }
  }
}

// K5: 1x1 conv 49->64 + BN + res2-add + ReLU -> O2 fp32.  LDS ~6 KB.
__global__ __launch_bounds__(256) void k5_conv22(
    const float* CO, const float* R2, float* O2,
    const float* w, const float* g, const float* bb) {
  __shared__ float As[49][32];
  int n = blockIdx.x / 98;
  int hw0 = (blockIdx.x % 98) * 32;
  const float* Cb = CO + n * 49 * 3136 + hw0;
  for (int idx = threadIdx.x; idx < 1568; idx += 256) {
    int r = idx >> 5, cl = idx & 31;
    As[r][cl] = Cb[r * 3136 + cl];
  }
  __syncthreads();
  int o = threadIdx.x >> 2;                     // 0..63
  int j0 = (threadIdx.x & 3) * 8;
  float a0=0.f,a1=0.f,a2=0.f,a3=0.f,a4=0.f,a5=0.f,a6=0.f,a7=0.f;
  const float* wr = w + o * 49;
  for (int c = 0; c < 49; c++) {
    float wv = wr[c];
    a0 = fmaf(wv, As[c][j0 + 0], a0);
    a1 = fmaf(wv, As[c][j0 + 1], a1);
    a2 = fmaf(wv, As[c][j0 + 2], a2);
    a3 = fmaf(wv, As[c][j0 + 3], a3);
    a4 = fmaf(wv, As[c][j0 + 4], a4);
    a5 = fmaf(wv, As[c][j0 + 5], a5);
    a6 = fmaf(wv, As[c][j0 + 6], a6);
    a7 = fmaf(wv, As[c][j0 + 7], a7);
  }
  float s = g[o] * MSC_BNI, bo = bb[o];
  int off = (n * 64 + o) * 3136 + hw0 + j0;
  O2[off + 0] = fmaxf(fmaf(a0, s, bo) + R2[off + 0], 0.f);
  O2[off + 1] = fmaxf(fmaf(a1, s, bo) + R2[off + 1], 0.f);
  O2[off + 2] = fmaxf(fmaf(a2, s, bo) + R2[off + 2], 0.f);
  O2[off + 3] = fmaxf(fmaf(a3, s, bo) + R2[off + 3], 0.f);
  O2[off + 4] = fmaxf(fmaf(a4, s, bo) + R2[off + 4], 0.f);
  O2[off + 5] = fmaxf(fmaf(a5, s, bo) + R2[off + 5], 0.f);
  O2[off + 6] = fmaxf(fmaf(a6, s, bo) + R2[off + 6], 0.f);
  O2[off + 7] = fmaxf(fmaf(a7, s, bo) + R2[off + 7], 0.f);
}

// K6: 3x3 conv 64->64 (cross-correlation, SAME) + BN + ReLU, + O2 -> C2 fp32.
// One block per (n, h-row); thread = (o, 14-col strip).  LDS 44.5 KB.
__global__ __launch_bounds__(256) void k6_conv2(
    const float* R2, const float* O2, float* C2,
    const float* wcv, const float* g, const float* bb) {
  __shared__ float sIn[64][3][58];              // ch, rows h-1..h+1, cols -1..56
  int n = blockIdx.x / 56;
  int h = blockIdx.x % 56;
  for (int idx = threadIdx.x; idx < 11136; idx += 256) {
    int ch = idx / 174;
    int rem = idx - ch * 174;
    int r = rem / 58;
    int cl = rem - r * 58;
    int gr = h - 1 + r, gc = cl - 1;
    float v = 0.f;
    if (gr >= 0 && gr < 56 && gc >= 0 && gc < 56)
      v = R2[(n * 64 + ch) * 3136 + gr * 56 + gc];
    sIn[ch][r][cl] = v;
  }
  __syncthreads();
  int o = threadIdx.x >> 2;                     // 0..63
  int w0 = (threadIdx.x & 3) * 14;              // column strip start
  float acc[14];
#pragma unroll
  for (int j = 0; j < 14; j++) acc[j] = 0.f;
  const float* wb = wcv + o * 576;              // [i][ky][kx]
  for (int c = 0; c < 64; c++) {
    const float* w9 = wb + c * 9;
    float k00 = w9[0], k01 = w9[1], k02 = w9[2];
    float k10 = w9[3], k11 = w9[4], k12 = w9[5];
    float k20 = w9[6], k21 = w9[7], k22 = w9[8];
#pragma unroll
    for (int j = 0; j < 14; j++) {
      int col = w0 + j;                         // sIn col = global col -1 .. +1
      float s0 = fmaf(k00, sIn[c][0][col], fmaf(k01, sIn[c][0][col + 1], k02 * sIn[c][0][col + 2]));
      float s1 = fmaf(k10, sIn[c][1][col], fmaf(k11, sIn[c][1][col + 1], k12 * sIn[c][1][col + 2]));
      float s2 = fmaf(k20, sIn[c][2][col], fmaf(k21, sIn[c][2][col + 1], k22 * sIn[c][2][col + 2]));
      acc[j] += s0 + s1 + s2;
    }
  }
  float s = g[o] * MSC_BNI, bo = bb[o];
  int off = (n * 64 + o) * 3136 + h * 56 + w0;
#pragma unroll
  for (int j = 0; j < 14; j++) {
    C2[off + j] = fmaxf(fmaf(acc[j], s, bo), 0.f) + O2[off + j];
  }
}

// K7: 1x1 conv 64->256 + BN + x-residual + ReLU -> d_out FP32.  LDS 4 KB.
__global__ __launch_bounds__(256) void k7_conv3(
    const float* C2, const float* x, float* outp,
    const float* w, const float* g, const float* bb) {
  __shared__ float As[64][16];
  int n = blockIdx.x / 196;
  int hw0 = (blockIdx.x % 196) * 16;
  const float* Cb = C2 + n * 64 * 3136 + hw0;
  for (int idx = threadIdx.x; idx < 1024; idx += 256) {
    int r = idx >> 4, cl = idx & 15;
    As[r][cl] = Cb[r * 3136 + cl];
  }
  __syncthreads();
  int o = threadIdx.x;                          // 0..255
  float acc[16];
#pragma unroll
  for (int j = 0; j < 16; j++) acc[j] = 0.f;
  const float* wr = w + o * 64;
  for (int c = 0; c < 64; c++) {
    float wv = wr[c];
#pragma unroll
    for (int j = 0; j < 16; j++) acc[j] = fmaf(wv, As[c][j], acc[j]);
  }
  float s = g[o] * MSC_BNI, bo = bb[o];
  int off = (n * 256 + o) * 3136 + hw0;
#pragma unroll
  for (int j = 0; j < 16; j++) {
    outp[off + j] = fmaxf(fmaf(acc[j], s, bo) + x[off + j], 0.f);
  }
}

extern "C" void kernel_launch(void* const* d_in, const int* in_sizes, int n_in,
                              void* d_out, int out_size, void* d_ws, size_t ws_size,
                              hipStream_t stream) {
  const float* x        = (const float*)d_in[0];
  const float* w1       = (const float*)d_in[1];
  const float* w3       = (const float*)d_in[2];
  const float* w5       = (const float*)d_in[3];
  const float* w7       = (const float*)d_in[4];
  const float* w_conv1  = (const float*)d_in[5];
  const float* g1       = (const float*)d_in[6];
  const float* b1       = (const float*)d_in[7];
  const float* w_conv21 = (const float*)d_in[8];
  const float* g21      = (const float*)d_in[9];
  const float* b21      = (const float*)d_in[10];
  const float* g22      = (const float*)d_in[11];
  const float* b22      = (const float*)d_in[12];
  const float* w_conv22 = (const float*)d_in[13];
  const float* g23      = (const float*)d_in[14];
  const float* b23      = (const float*)d_in[15];
  const float* w_conv2  = (const float*)d_in[16];
  const float* g2       = (const float*)d_in[17];
  const float* b2       = (const float*)d_in[18];
  const float* w_conv3  = (const float*)d_in[19];
  const float* g3       = (const float*)d_in[20];
  const float* b3       = (const float*)d_in[21];

  // d_out is FP32: 51,380,224 elements = 205,520,896 B. It doubles as scratch
  // for buffers dead before K7's full overwrite:
  //   A  bf16 [0 .. 102,760,448)           K1 w, K2 r
  //   Y  fp32 [0 .. 12,845,056)            K3 w, K4 r   (A dead)
  //   CO fp32 [12,845,056 .. 52,183,040)   K4 w, K5 r
  //   O2 fp32 [52,183,040 .. 103,563,264)  K5 w, K6 r
  //   out fp32 (all 205,520,896)           K7 w
  // d_ws: R2 fp32 [0 .. 51,380,224), C2 fp32 [51,380,224 .. 102,760,448)
  char* ob = (char*)d_out;
  char* ws = (char*)d_ws;
  unsigned short* A  = (unsigned short*)ob;
  float*          Yv = (float*)ob;
  float*          CO = (float*)(ob + 12845056);
  float*          O2 = (float*)(ob + 52183040);
  float*          R2 = (float*)ws;
  float*          C2 = (float*)(ws + 51380224);

  k1_tconv <<<dim3(25088),    dim3(256), 0, stream>>>(x, A, w1, w3, w5, w7);
  k2_conv1 <<<dim3(64 * 196), dim3(256), 0, stream>>>(A, R2, w_conv1, g1, b1);
  k3_conv21<<<dim3(64 * 49),  dim3(256), 0, stream>>>(R2, Yv, w_conv21, g21, b21);
  k4_corr  <<<dim3(64 * 14),  dim3(256), 0, stream>>>(Yv, CO, g22, b22);
  k5_conv22<<<dim3(64 * 98),  dim3(256), 0, stream>>>(CO, R2, O2, w_conv22, g23, b23);
  k6_conv2 <<<dim3(64 * 56),  dim3(256), 0, stream>>>(R2, O2, C2, w_conv2, g2, b2);
  k7_conv3 <<<dim3(64 * 196), dim3(256), 0, stream>>>(C2, x, (float*)d_out, w_conv3, g3, b3);
}